// Round 19
// baseline (85.725 us; speedup 1.0000x reference)
//
#include <hip/hip_runtime.h>

#define TB 256
#define NA_G (32 * 12 * 1024)   // 16B-groups in A tiles
#define NB_G (64 * 12 * 1024)   // 16B-groups in B tiles
#define NEED_T ((size_t)(NA_G + NB_G) * 16)          // 18.87 MB bf16 tiles

typedef __bf16 bf16x8 __attribute__((ext_vector_type(8)));
typedef float f32x16 __attribute__((ext_vector_type(16)));
typedef unsigned long long ull;

__device__ __forceinline__ unsigned pack2bf(float a, float b) {
  unsigned ua = __float_as_uint(a), ub = __float_as_uint(b);
  ua = (ua + 0x7fffu + ((ua >> 16) & 1u)) >> 16;   // RNE f32->bf16
  ub = (ub + 0x7fffu + ((ub >> 16) & 1u)) >> 16;
  return ua | (ub << 16);
}
__device__ __forceinline__ void gll16(const void* g, void* l) {
  __builtin_amdgcn_global_load_lds(
      (const __attribute__((address_space(1))) unsigned*)g,
      (__attribute__((address_space(3))) unsigned*)l, 16, 0, 0);
}

// Pre-convert f32 -> bf16 into XOR-swizzled 128x64 tiles (LDS-image layout)
__global__ __launch_bounds__(256) void convert_pack(
    const float* __restrict__ q, const float* __restrict__ p,
    unsigned char* __restrict__ qt, unsigned char* __restrict__ pt) {
  int g = blockIdx.x * 256 + threadIdx.x;
  const float* src;
  unsigned char* dst;
  if (g < NA_G) { src = q; dst = qt; }
  else { g -= NA_G; src = p; dst = pt; }
  int tile = g >> 10;
  int o = (g & 1023) * 16;
  int row = o >> 7;
  int colb = (o & 127) ^ ((row & 7) << 4);
  int rb = tile / 12, kt = tile - rb * 12;
  const float* s = src + ((size_t)(rb * 128 + row)) * 768 + kt * 64 + (colb >> 1);
  float4 a = ((const float4*)s)[0];
  float4 b = ((const float4*)s)[1];
  uint4 w;
  w.x = pack2bf(a.x, a.y); w.y = pack2bf(a.z, a.w);
  w.z = pack2bf(b.x, b.y); w.w = pack2bf(b.z, b.w);
  *(uint4*)(dst + (size_t)tile * 16384 + o) = w;
}

// ===== fused: 32x32x16-MFMA GEMM -> acc-direct 2-pass PACKED-hist select =====
// 32x32x16 bf16 MFMA: half the MFMA instructions, ~20% fewer matrix-pipe
// cycles vs 16x16x32 (m119: 2495 vs 2176 TF). Selection is histogram-based
// (order-agnostic): only the validity mapping tracks the new C/D layout
// col=lane&31, row=(reg&3)+8*(reg>>2)+4*(lane>>5)  [verified m74/m101].
// Pass B: ONE packed int atomic (1<<20)|(q&255); cnt<=4095<2^12, lowsum<2^20.
template <int PATH>
__global__ __launch_bounds__(TB, 4) void dpr_fused(
    const float* __restrict__ q_emb, const float* __restrict__ p_emb,
    const void* __restrict__ qmr, const void* __restrict__ pmr,
    const float* __restrict__ alpha_raw, const float* __restrict__ beta_raw,
    const unsigned char* __restrict__ qt, const unsigned char* __restrict__ pt,
    float* __restrict__ out) {
  __shared__ __align__(16) char arena[32768];  // GEMM: Al|Bl ; then 1KB hist/wave
  unsigned short* Al = (unsigned short*)arena;
  unsigned short* Bl = (unsigned short*)(arena + 16384);

  const int tid = threadIdx.x, lane = tid & 63, wid = tid >> 6;
  // XCD-clustered bid map: 8 regions of 16x16 block-tiles
  int g = blockIdx.x;
  int rg = g & 7, w = g >> 3;
  const int blockB = (rg >> 2) * 16 + (w & 15);
  const int blockP = (rg & 3) * 16 + (w >> 4);
  const int lo5 = lane & 31, hi = lane >> 5;
  const int db = wid >> 1, dp = wid & 1;

  // ---- per-wave masks (dtype sniffed) ----
  bool m32 = true;
  {
    const unsigned* qm32 = (const unsigned*)qmr;
    #pragma unroll
    for (int i = 0; i < 8; ++i) m32 = m32 && (qm32[i] <= 1u);
  }
  int qrow = (blockB * 2 + db) * 64 + lane;
  int pcolg = (blockP * 2 + dp) * 64 + lane;
  bool qvb = m32 ? (((const int*)qmr)[qrow] != 0) : (((const unsigned char*)qmr)[qrow] != 0);
  bool pvb = m32 ? (((const int*)pmr)[pcolg] != 0) : (((const unsigned char*)pmr)[pcolg] != 0);
  ull qb = __ballot(qvb);
  ull pb = __ballot(pvb);
  const int n_pair = __popcll(qb) * __popcll(pb);

  // ---- GEMM: 128x128 block tile, each wave owns one 64x64 pair ----
  f32x16 acc[2][2];
  #pragma unroll
  for (int m = 0; m < 2; ++m)
    #pragma unroll
    for (int n = 0; n < 2; ++n)
      #pragma unroll
      for (int r = 0; r < 16; ++r) acc[m][n][r] = 0.f;

  const float* Abase = q_emb + (size_t)(blockB * 128) * 768;
  const float* Bbase = p_emb + (size_t)(blockP * 128) * 768;

  for (int kt = 0; kt < 12; ++kt) {
    if (PATH == 1) {
      const unsigned char* qtile = qt + ((size_t)(blockB * 12 + kt)) * 16384;
      const unsigned char* ptile = pt + ((size_t)(blockP * 12 + kt)) * 16384;
      #pragma unroll
      for (int c2 = 0; c2 < 4; ++c2) {
        int chunk = wid * 4 + c2;
        gll16(qtile + chunk * 1024 + lane * 16, (char*)Al + chunk * 1024);
        gll16(ptile + chunk * 1024 + lane * 16, (char*)Bl + chunk * 1024);
      }
    } else {
      const int k0 = kt * 64;
      #pragma unroll
      for (int it = 0; it < 4; ++it) {
        int gg = tid + 256 * it;
        int row = gg >> 3;
        int col = (gg & 7) * 8;
        int off = (row * 128 + col * 2) ^ ((row & 7) << 4);
        const float4* sA = (const float4*)(Abase + (size_t)row * 768 + k0 + col);
        float4 a0 = sA[0], a1 = sA[1];
        uint4 wv;
        wv.x = pack2bf(a0.x, a0.y); wv.y = pack2bf(a0.z, a0.w);
        wv.z = pack2bf(a1.x, a1.y); wv.w = pack2bf(a1.z, a1.w);
        *(uint4*)((char*)Al + off) = wv;
        const float4* sB = (const float4*)(Bbase + (size_t)row * 768 + k0 + col);
        float4 b0 = sB[0], b1 = sB[1];
        wv.x = pack2bf(b0.x, b0.y); wv.y = pack2bf(b0.z, b0.w);
        wv.z = pack2bf(b1.x, b1.y); wv.w = pack2bf(b1.z, b1.w);
        *(uint4*)((char*)Bl + off) = wv;
      }
    }
    __syncthreads();
    #pragma unroll
    for (int ks = 0; ks < 4; ++ks) {   // four K=16 steps per 64-wide tile
      bf16x8 af[2], bfr[2];
      #pragma unroll
      for (int m = 0; m < 2; ++m) {
        int row = db * 64 + m * 32 + lo5;
        int off = (row * 128 + ks * 32 + hi * 16) ^ ((row & 7) << 4);
        af[m] = *(const bf16x8*)((const char*)Al + off);
      }
      #pragma unroll
      for (int n = 0; n < 2; ++n) {
        int row = dp * 64 + n * 32 + lo5;
        int off = (row * 128 + ks * 32 + hi * 16) ^ ((row & 7) << 4);
        bfr[n] = *(const bf16x8*)((const char*)Bl + off);
      }
      #pragma unroll
      for (int m = 0; m < 2; ++m)
        #pragma unroll
        for (int n = 0; n < 2; ++n)
          acc[m][n] = __builtin_amdgcn_mfma_f32_32x32x16_bf16(af[m], bfr[n], acc[m][n], 0, 0, 0);
    }
    __syncthreads();   // final barrier also fences arena reuse below
  }

  const int outIdx = (blockB * 2 + db) * 128 + (blockP * 2 + dp);
  if (n_pair == 0) {
    if (lane == 0) out[outIdx] = -1e9f;
    return;
  }

  // per-lane validity for (m,n,reg): q-row = m*32 + (reg&3)+8*(reg>>2)+4*hi,
  // p-col = n*32 + lo5.  idx = (m*2+n)*16 + reg.
  unsigned vlo = 0, vhi2 = 0;
  {
    unsigned pcn[2];
    #pragma unroll
    for (int n = 0; n < 2; ++n)
      pcn[n] = ((pb >> (n * 32 + lo5)) & 1ull) ? 0xFFFFu : 0u;
    #pragma unroll
    for (int m = 0; m < 2; ++m) {
      unsigned chunk = 0;
      #pragma unroll
      for (int g2 = 0; g2 < 4; ++g2)
        chunk |= (unsigned)((qb >> (m * 32 + hi * 4 + 8 * g2)) & 0xFull) << (4 * g2);
      unsigned wmask = (chunk & pcn[0]) | ((chunk & pcn[1]) << 16);
      if (m == 0) vlo = wmask; else vhi2 = wmask;
    }
  }
  #define VBIT(idx) ((idx) < 32 ? ((vlo >> (idx)) & 1u) : ((vhi2 >> ((idx) - 32)) & 1u))

  int ksel = 4 * n_pair / 10; if (ksel < 1) ksel = 1;
  int lsel = 2 * n_pair / 10; if (lsel < 1) lsel = 1;

  // packed hist aliases the dead arena; wave-private 1KB
  unsigned* c1 = (unsigned*)(arena + wid * 8192);

  // Pass A: masked min / max over acc (registers + shfl)
  float mn = INFINITY, mx = -INFINITY;
  #pragma unroll
  for (int m = 0; m < 2; ++m)
    #pragma unroll
    for (int n = 0; n < 2; ++n)
      #pragma unroll
      for (int r = 0; r < 16; ++r) {
        const int idx = (m * 2 + n) * 16 + r;
        float x = acc[m][n][r];
        if (VBIT(idx)) { mn = fminf(mn, x); mx = fmaxf(mx, x); }
      }
  #pragma unroll
  for (int off = 1; off < 64; off <<= 1) {
    mn = fminf(mn, __shfl_xor(mn, off));
    mx = fmaxf(mx, __shfl_xor(mx, off));
  }

  float tsum, topS, botS;
  if (!(mx > mn)) {
    tsum = (float)n_pair * mn;        // all valid values identical
    topS = (float)ksel * mn;
    botS = (float)lsel * mn;
  } else {
    const float sc16 = 65535.0f / (mx - mn);
    const float inv16 = (mx - mn) * (1.0f / 65535.0f);

    // zero hist (same-wave in-order)
    ((uint4*)c1)[lane] = uint4{0u, 0u, 0u, 0u};

    // Pass B: ONE masked packed atomic per acc element
    #pragma unroll
    for (int m = 0; m < 2; ++m)
      #pragma unroll
      for (int n = 0; n < 2; ++n)
        #pragma unroll
        for (int r = 0; r < 16; ++r) {
          const int idx = (m * 2 + n) * 16 + r;
          if (VBIT(idx)) {
            int q = (int)((acc[m][n][r] - mn) * sc16);
            q = q < 0 ? 0 : (q > 65535 ? 65535 : q);
            atomicAdd(&c1[q >> 8], (1u << 20) | (unsigned)(q & 255));
          }
        }

    // unpack lane's 4 bins; reconstruct exact per-bin fixsum
    uint4 wq = ((const uint4*)c1)[lane];
    const unsigned cl0 = wq.x >> 20, cl1 = wq.y >> 20, cl2 = wq.z >> 20, cl3 = wq.w >> 20;
    const int b0i = lane * 4;
    const unsigned fl0 = (wq.x & 0xFFFFFu) + cl0 * ((unsigned)(b0i + 0) << 8);
    const unsigned fl1 = (wq.y & 0xFFFFFu) + cl1 * ((unsigned)(b0i + 1) << 8);
    const unsigned fl2 = (wq.z & 0xFFFFFu) + cl2 * ((unsigned)(b0i + 2) << 8);
    const unsigned fl3 = (wq.w & 0xFFFFFu) + cl3 * ((unsigned)(b0i + 3) << 8);
    const unsigned lc = cl0 + cl1 + cl2 + cl3;
    const unsigned lf = fl0 + fl1 + fl2 + fl3;
    unsigned runC = lc, runF = lf;
    #pragma unroll
    for (int off = 1; off < 64; off <<= 1) {
      unsigned o = __shfl_down(runC, off);
      unsigned of = __shfl_down(runF, off);
      if (lane + off < 64) { runC += o; runF += of; }
    }
    const unsigned totC = __shfl(runC, 0);
    const unsigned totF = __shfl(runF, 0);
    tsum = (float)totF * inv16 + (float)totC * mn;   // totC == n_pair

    // top locate (suffix: high bins first), carrying fix-sum-above
    unsigned aboveC = runC - lc, aboveF = runF - lf;
    bool fT = ((unsigned)ksel > aboveC) && ((unsigned)ksel <= runC);
    int RT_ = 0; unsigned saF_ = 0u, bcT_ = 0u, bfT_ = 0u;
    if (fT) {
      unsigned a = aboveC, af = aboveF;
      if ((unsigned)ksel <= a + cl3) { RT_ = (int)((unsigned)ksel - a); saF_ = af; bcT_ = cl3; bfT_ = fl3; }
      else { a += cl3; af += fl3;
      if ((unsigned)ksel <= a + cl2) { RT_ = (int)((unsigned)ksel - a); saF_ = af; bcT_ = cl2; bfT_ = fl2; }
      else { a += cl2; af += fl2;
      if ((unsigned)ksel <= a + cl1) { RT_ = (int)((unsigned)ksel - a); saF_ = af; bcT_ = cl1; bfT_ = fl1; }
      else { a += cl1; af += fl1; RT_ = (int)((unsigned)ksel - a); saF_ = af; bcT_ = cl0; bfT_ = fl0; } } }
    }
    ull fmT = __ballot(fT);
    int srcT = fmT ? (int)__builtin_ctzll(fmT) : 0;
    const int RT = __shfl(RT_, srcT);
    const unsigned saFT = __shfl(saF_, srcT);
    const unsigned cT = __shfl(bcT_, srcT);
    const unsigned bFixT = __shfl(bfT_, srcT);

    // bottom locate (prefix: low bins first), carrying fix-sum-below
    unsigned belowC = totC - runC, belowF = totF - runF;
    bool fB = ((unsigned)lsel > belowC) && ((unsigned)lsel <= belowC + lc);
    int RB_ = 0; unsigned sbF_ = 0u, bcB_ = 0u, bfB_ = 0u;
    if (fB) {
      unsigned a = belowC, af = belowF;
      if ((unsigned)lsel <= a + cl0) { RB_ = (int)((unsigned)lsel - a); sbF_ = af; bcB_ = cl0; bfB_ = fl0; }
      else { a += cl0; af += fl0;
      if ((unsigned)lsel <= a + cl1) { RB_ = (int)((unsigned)lsel - a); sbF_ = af; bcB_ = cl1; bfB_ = fl1; }
      else { a += cl1; af += fl1;
      if ((unsigned)lsel <= a + cl2) { RB_ = (int)((unsigned)lsel - a); sbF_ = af; bcB_ = cl2; bfB_ = fl2; }
      else { a += cl2; af += fl2; RB_ = (int)((unsigned)lsel - a); sbF_ = af; bcB_ = cl3; bfB_ = fl3; } } }
    }
    ull fmB = __ballot(fB);
    int srcB = fmB ? (int)__builtin_ctzll(fmB) : 0;
    const int RB = __shfl(RB_, srcB);
    const unsigned sbFB = __shfl(sbF_, srcB);
    const unsigned cB = __shfl(bcB_, srcB);
    const unsigned bFixB = __shfl(bfB_, srcB);

    // tail = bin fix-mean * rank-in-bin; convert fix -> value domain
    float topFix = (float)saFT + (float)bFixT * ((float)RT / (float)cT);
    float botFix = (float)sbFB + (float)bFixB * ((float)RB / (float)cB);
    topS = topFix * inv16 + (float)ksel * mn;
    botS = botFix * inv16 + (float)lsel * mn;
  }
  #undef VBIT

  if (lane == 0) {
    float alpha = log1pf(expf(alpha_raw[0]));
    float beta = log1pf(expf(beta_raw[0]));
    float total_mean = tsum / (float)n_pair;
    float top_mean = topS / (float)ksel;
    float bm = fmaxf(0.0f, -(botS / (float)lsel));
    out[outIdx] = total_mean + alpha * top_mean - beta * bm;
  }
}

extern "C" void kernel_launch(void* const* d_in, const int* in_sizes, int n_in,
                              void* d_out, int out_size, void* d_ws, size_t ws_size,
                              hipStream_t stream) {
  (void)in_sizes; (void)n_in; (void)out_size;
  const float* q_emb = (const float*)d_in[0];
  const float* p_emb = (const float*)d_in[1];
  const void* q_mask = d_in[2];
  const void* p_mask = d_in[3];
  const float* alpha_raw = (const float*)d_in[4];
  const float* beta_raw = (const float*)d_in[5];
  float* out = (float*)d_out;

  if (ws_size >= NEED_T) {
    unsigned char* qt = (unsigned char*)d_ws;
    unsigned char* pt = qt + (size_t)NA_G * 16;
    hipLaunchKernelGGL(convert_pack, dim3((NA_G + NB_G) / 256), dim3(256), 0, stream,
                       q_emb, p_emb, qt, pt);
    hipLaunchKernelGGL((dpr_fused<1>), dim3(2048), dim3(TB), 0, stream,
                       q_emb, p_emb, q_mask, p_mask, alpha_raw, beta_raw, qt, pt, out);
  } else {
    hipLaunchKernelGGL((dpr_fused<0>), dim3(2048), dim3(TB), 0, stream,
                       q_emb, p_emb, q_mask, p_mask, alpha_raw, beta_raw,
                       (const unsigned char*)nullptr, (const unsigned char*)nullptr, out);
  }
}

// Round 20
// 81.642 us; speedup vs baseline: 1.0500x; 1.0500x over previous
//
#include <hip/hip_runtime.h>

#define TB 256
#define NA_G (32 * 12 * 1024)   // 16B-groups in A tiles
#define NB_G (64 * 12 * 1024)   // 16B-groups in B tiles
#define NEED_T ((size_t)(NA_G + NB_G) * 16)          // 18.87 MB bf16 tiles

typedef __bf16 bf16x8 __attribute__((ext_vector_type(8)));
typedef float f32x4 __attribute__((ext_vector_type(4)));
typedef unsigned long long ull;

__device__ __forceinline__ unsigned pack2bf(float a, float b) {
  unsigned ua = __float_as_uint(a), ub = __float_as_uint(b);
  ua = (ua + 0x7fffu + ((ua >> 16) & 1u)) >> 16;   // RNE f32->bf16
  ub = (ub + 0x7fffu + ((ub >> 16) & 1u)) >> 16;
  return ua | (ub << 16);
}
__device__ __forceinline__ void gll16(const void* g, void* l) {
  __builtin_amdgcn_global_load_lds(
      (const __attribute__((address_space(1))) unsigned*)g,
      (__attribute__((address_space(3))) unsigned*)l, 16, 0, 0);
}

// Pre-convert f32 -> bf16 into XOR-swizzled 128x64 tiles (LDS-image layout)
__global__ __launch_bounds__(256) void convert_pack(
    const float* __restrict__ q, const float* __restrict__ p,
    unsigned char* __restrict__ qt, unsigned char* __restrict__ pt) {
  int g = blockIdx.x * 256 + threadIdx.x;
  const float* src;
  unsigned char* dst;
  if (g < NA_G) { src = q; dst = qt; }
  else { g -= NA_G; src = p; dst = pt; }
  int tile = g >> 10;
  int o = (g & 1023) * 16;
  int row = o >> 7;
  int colb = (o & 127) ^ ((row & 7) << 4);
  int rb = tile / 12, kt = tile - rb * 12;
  const float* s = src + ((size_t)(rb * 128 + row)) * 768 + kt * 64 + (colb >> 1);
  float4 a = ((const float4*)s)[0];
  float4 b = ((const float4*)s)[1];
  uint4 w;
  w.x = pack2bf(a.x, a.y); w.y = pack2bf(a.z, a.w);
  w.z = pack2bf(b.x, b.y); w.w = pack2bf(b.z, b.w);
  *(uint4*)(dst + (size_t)tile * 16384 + o) = w;
}

// ===== fused: GEMM -> acc-direct 2-pass PACKED-hist select (no handoff) =====
// R18 configuration (measured best: 74.1 us fused). 16x16x32 MFMA (32x32
// variant regresses: 32-row fragment reads exceed the 8-slot swizzle spread
// -> inherent 4-way LDS read conflicts, R19). Selection runs straight on the
// AGPR accumulators: Pass A (masked min/max), Pass B (masked quantize + ONE
// packed int atomic: (1<<20)|(q&255)). Capacity: mx>mn => bins 0,255
// occupied => cnt<=4095<2^12, lowsum<2^20. Per-bin fixsum =
// cnt*(bin*256)+lowsum, exact in quantized domain. Float LDS atomics banned
// (CAS-loop, R10/R11).
template <int PATH>
__global__ __launch_bounds__(TB, 4) void dpr_fused(
    const float* __restrict__ q_emb, const float* __restrict__ p_emb,
    const void* __restrict__ qmr, const void* __restrict__ pmr,
    const float* __restrict__ alpha_raw, const float* __restrict__ beta_raw,
    const unsigned char* __restrict__ qt, const unsigned char* __restrict__ pt,
    float* __restrict__ out) {
  __shared__ __align__(16) char arena[32768];  // GEMM: Al|Bl ; then 1KB hist/wave
  unsigned short* Al = (unsigned short*)arena;
  unsigned short* Bl = (unsigned short*)(arena + 16384);

  const int tid = threadIdx.x, lane = tid & 63, wid = tid >> 6;
  // XCD-clustered bid map: 8 regions of 16x16 block-tiles
  int g = blockIdx.x;
  int rg = g & 7, w = g >> 3;
  const int blockB = (rg >> 2) * 16 + (w & 15);
  const int blockP = (rg & 3) * 16 + (w >> 4);
  const int lr = lane & 15, lg = lane >> 4;
  const int db = wid >> 1, dp = wid & 1;

  // ---- per-wave masks (dtype sniffed) ----
  bool m32 = true;
  {
    const unsigned* qm32 = (const unsigned*)qmr;
    #pragma unroll
    for (int i = 0; i < 8; ++i) m32 = m32 && (qm32[i] <= 1u);
  }
  int qrow = (blockB * 2 + db) * 64 + lane;
  int pcolg = (blockP * 2 + dp) * 64 + lane;
  bool qvb = m32 ? (((const int*)qmr)[qrow] != 0) : (((const unsigned char*)qmr)[qrow] != 0);
  bool pvb = m32 ? (((const int*)pmr)[pcolg] != 0) : (((const unsigned char*)pmr)[pcolg] != 0);
  ull qb = __ballot(qvb);
  ull pb = __ballot(pvb);
  const int n_pair = __popcll(qb) * __popcll(pb);

  // ---- GEMM: 128x128 block tile, each wave owns one 64x64 pair ----
  f32x4 acc[4][4];
  #pragma unroll
  for (int m = 0; m < 4; ++m)
    #pragma unroll
    for (int n = 0; n < 4; ++n)
      acc[m][n] = f32x4{0.f, 0.f, 0.f, 0.f};

  const float* Abase = q_emb + (size_t)(blockB * 128) * 768;
  const float* Bbase = p_emb + (size_t)(blockP * 128) * 768;

  for (int kt = 0; kt < 12; ++kt) {
    if (PATH == 1) {
      const unsigned char* qtile = qt + ((size_t)(blockB * 12 + kt)) * 16384;
      const unsigned char* ptile = pt + ((size_t)(blockP * 12 + kt)) * 16384;
      #pragma unroll
      for (int c2 = 0; c2 < 4; ++c2) {
        int chunk = wid * 4 + c2;
        gll16(qtile + chunk * 1024 + lane * 16, (char*)Al + chunk * 1024);
        gll16(ptile + chunk * 1024 + lane * 16, (char*)Bl + chunk * 1024);
      }
    } else {
      const int k0 = kt * 64;
      #pragma unroll
      for (int it = 0; it < 4; ++it) {
        int gg = tid + 256 * it;
        int row = gg >> 3;
        int col = (gg & 7) * 8;
        int off = (row * 128 + col * 2) ^ ((row & 7) << 4);
        const float4* sA = (const float4*)(Abase + (size_t)row * 768 + k0 + col);
        float4 a0 = sA[0], a1 = sA[1];
        uint4 wv;
        wv.x = pack2bf(a0.x, a0.y); wv.y = pack2bf(a0.z, a0.w);
        wv.z = pack2bf(a1.x, a1.y); wv.w = pack2bf(a1.z, a1.w);
        *(uint4*)((char*)Al + off) = wv;
        const float4* sB = (const float4*)(Bbase + (size_t)row * 768 + k0 + col);
        float4 b0 = sB[0], b1 = sB[1];
        wv.x = pack2bf(b0.x, b0.y); wv.y = pack2bf(b0.z, b0.w);
        wv.z = pack2bf(b1.x, b1.y); wv.w = pack2bf(b1.z, b1.w);
        *(uint4*)((char*)Bl + off) = wv;
      }
    }
    __syncthreads();
    #pragma unroll
    for (int ks = 0; ks < 2; ++ks) {
      bf16x8 af[4], bfr[4];
      #pragma unroll
      for (int m = 0; m < 4; ++m) {
        int row = db * 64 + m * 16 + lr;
        int off = (row * 128 + ks * 64 + lg * 16) ^ ((row & 7) << 4);
        af[m] = *(const bf16x8*)((const char*)Al + off);
      }
      #pragma unroll
      for (int n = 0; n < 4; ++n) {
        int row = dp * 64 + n * 16 + lr;
        int off = (row * 128 + ks * 64 + lg * 16) ^ ((row & 7) << 4);
        bfr[n] = *(const bf16x8*)((const char*)Bl + off);
      }
      #pragma unroll
      for (int m = 0; m < 4; ++m)
        #pragma unroll
        for (int n = 0; n < 4; ++n)
          acc[m][n] = __builtin_amdgcn_mfma_f32_16x16x32_bf16(af[m], bfr[n], acc[m][n], 0, 0, 0);
    }
    __syncthreads();   // final barrier also fences arena reuse below
  }

  const int outIdx = (blockB * 2 + db) * 128 + (blockP * 2 + dp);
  if (n_pair == 0) {
    if (lane == 0) out[outIdx] = -1e9f;
    return;
  }

  // per-lane validity of the 64 owned elements (idx=(m*4+n)*4+j)
  unsigned vlo = 0, vhi = 0;
  {
    unsigned qn[4], pc[4];
    #pragma unroll
    for (int m = 0; m < 4; ++m) qn[m] = (unsigned)((qb >> (m * 16 + lg * 4)) & 0xFull);
    #pragma unroll
    for (int n = 0; n < 4; ++n) pc[n] = ((pb >> (n * 16 + lr)) & 1ull) ? 0xFu : 0u;
    #pragma unroll
    for (int m = 0; m < 2; ++m)
      #pragma unroll
      for (int n = 0; n < 4; ++n) vlo |= (qn[m] & pc[n]) << ((m * 4 + n) * 4);
    #pragma unroll
    for (int m = 2; m < 4; ++m)
      #pragma unroll
      for (int n = 0; n < 4; ++n) vhi |= (qn[m] & pc[n]) << (((m - 2) * 4 + n) * 4);
  }
  #define VBIT(idx) ((idx) < 32 ? ((vlo >> (idx)) & 1u) : ((vhi >> ((idx) - 32)) & 1u))

  int ksel = 4 * n_pair / 10; if (ksel < 1) ksel = 1;
  int lsel = 2 * n_pair / 10; if (lsel < 1) lsel = 1;

  // packed hist aliases the dead arena; wave-private 1KB
  unsigned* c1 = (unsigned*)(arena + wid * 8192);

  // Pass A: masked min / max over acc (registers + shfl)
  float mn = INFINITY, mx = -INFINITY;
  #pragma unroll
  for (int m = 0; m < 4; ++m)
    #pragma unroll
    for (int n = 0; n < 4; ++n)
      #pragma unroll
      for (int j = 0; j < 4; ++j) {
        const int idx = (m * 4 + n) * 4 + j;
        float x = acc[m][n][j];
        if (VBIT(idx)) { mn = fminf(mn, x); mx = fmaxf(mx, x); }
      }
  #pragma unroll
  for (int off = 1; off < 64; off <<= 1) {
    mn = fminf(mn, __shfl_xor(mn, off));
    mx = fmaxf(mx, __shfl_xor(mx, off));
  }

  float tsum, topS, botS;
  if (!(mx > mn)) {
    tsum = (float)n_pair * mn;        // all valid values identical
    topS = (float)ksel * mn;
    botS = (float)lsel * mn;
  } else {
    const float sc16 = 65535.0f / (mx - mn);
    const float inv16 = (mx - mn) * (1.0f / 65535.0f);

    // zero hist (same-wave in-order)
    ((uint4*)c1)[lane] = uint4{0u, 0u, 0u, 0u};

    // Pass B: ONE masked packed atomic per acc element
    #pragma unroll
    for (int m = 0; m < 4; ++m)
      #pragma unroll
      for (int n = 0; n < 4; ++n)
        #pragma unroll
        for (int j = 0; j < 4; ++j) {
          const int idx = (m * 4 + n) * 4 + j;
          if (VBIT(idx)) {
            int q = (int)((acc[m][n][j] - mn) * sc16);
            q = q < 0 ? 0 : (q > 65535 ? 65535 : q);
            atomicAdd(&c1[q >> 8], (1u << 20) | (unsigned)(q & 255));
          }
        }

    // unpack lane's 4 bins; reconstruct exact per-bin fixsum
    uint4 wq = ((const uint4*)c1)[lane];
    const unsigned cl0 = wq.x >> 20, cl1 = wq.y >> 20, cl2 = wq.z >> 20, cl3 = wq.w >> 20;
    const int b0i = lane * 4;
    const unsigned fl0 = (wq.x & 0xFFFFFu) + cl0 * ((unsigned)(b0i + 0) << 8);
    const unsigned fl1 = (wq.y & 0xFFFFFu) + cl1 * ((unsigned)(b0i + 1) << 8);
    const unsigned fl2 = (wq.z & 0xFFFFFu) + cl2 * ((unsigned)(b0i + 2) << 8);
    const unsigned fl3 = (wq.w & 0xFFFFFu) + cl3 * ((unsigned)(b0i + 3) << 8);
    const unsigned lc = cl0 + cl1 + cl2 + cl3;
    const unsigned lf = fl0 + fl1 + fl2 + fl3;
    unsigned runC = lc, runF = lf;
    #pragma unroll
    for (int off = 1; off < 64; off <<= 1) {
      unsigned o = __shfl_down(runC, off);
      unsigned of = __shfl_down(runF, off);
      if (lane + off < 64) { runC += o; runF += of; }
    }
    const unsigned totC = __shfl(runC, 0);
    const unsigned totF = __shfl(runF, 0);
    tsum = (float)totF * inv16 + (float)totC * mn;   // totC == n_pair

    // top locate (suffix: high bins first), carrying fix-sum-above
    unsigned aboveC = runC - lc, aboveF = runF - lf;
    bool fT = ((unsigned)ksel > aboveC) && ((unsigned)ksel <= runC);
    int RT_ = 0; unsigned saF_ = 0u, bcT_ = 0u, bfT_ = 0u;
    if (fT) {
      unsigned a = aboveC, af = aboveF;
      if ((unsigned)ksel <= a + cl3) { RT_ = (int)((unsigned)ksel - a); saF_ = af; bcT_ = cl3; bfT_ = fl3; }
      else { a += cl3; af += fl3;
      if ((unsigned)ksel <= a + cl2) { RT_ = (int)((unsigned)ksel - a); saF_ = af; bcT_ = cl2; bfT_ = fl2; }
      else { a += cl2; af += fl2;
      if ((unsigned)ksel <= a + cl1) { RT_ = (int)((unsigned)ksel - a); saF_ = af; bcT_ = cl1; bfT_ = fl1; }
      else { a += cl1; af += fl1; RT_ = (int)((unsigned)ksel - a); saF_ = af; bcT_ = cl0; bfT_ = fl0; } } }
    }
    ull fmT = __ballot(fT);
    int srcT = fmT ? (int)__builtin_ctzll(fmT) : 0;
    const int RT = __shfl(RT_, srcT);
    const unsigned saFT = __shfl(saF_, srcT);
    const unsigned cT = __shfl(bcT_, srcT);
    const unsigned bFixT = __shfl(bfT_, srcT);

    // bottom locate (prefix: low bins first), carrying fix-sum-below
    unsigned belowC = totC - runC, belowF = totF - runF;
    bool fB = ((unsigned)lsel > belowC) && ((unsigned)lsel <= belowC + lc);
    int RB_ = 0; unsigned sbF_ = 0u, bcB_ = 0u, bfB_ = 0u;
    if (fB) {
      unsigned a = belowC, af = belowF;
      if ((unsigned)lsel <= a + cl0) { RB_ = (int)((unsigned)lsel - a); sbF_ = af; bcB_ = cl0; bfB_ = fl0; }
      else { a += cl0; af += fl0;
      if ((unsigned)lsel <= a + cl1) { RB_ = (int)((unsigned)lsel - a); sbF_ = af; bcB_ = cl1; bfB_ = fl1; }
      else { a += cl1; af += fl1;
      if ((unsigned)lsel <= a + cl2) { RB_ = (int)((unsigned)lsel - a); sbF_ = af; bcB_ = cl2; bfB_ = fl2; }
      else { a += cl2; af += fl2; RB_ = (int)((unsigned)lsel - a); sbF_ = af; bcB_ = cl3; bfB_ = fl3; } } }
    }
    ull fmB = __ballot(fB);
    int srcB = fmB ? (int)__builtin_ctzll(fmB) : 0;
    const int RB = __shfl(RB_, srcB);
    const unsigned sbFB = __shfl(sbF_, srcB);
    const unsigned cB = __shfl(bcB_, srcB);
    const unsigned bFixB = __shfl(bfB_, srcB);

    // tail = bin fix-mean * rank-in-bin; convert fix -> value domain
    float topFix = (float)saFT + (float)bFixT * ((float)RT / (float)cT);
    float botFix = (float)sbFB + (float)bFixB * ((float)RB / (float)cB);
    topS = topFix * inv16 + (float)ksel * mn;
    botS = botFix * inv16 + (float)lsel * mn;
  }
  #undef VBIT

  if (lane == 0) {
    float alpha = log1pf(expf(alpha_raw[0]));
    float beta = log1pf(expf(beta_raw[0]));
    float total_mean = tsum / (float)n_pair;
    float top_mean = topS / (float)ksel;
    float bm = fmaxf(0.0f, -(botS / (float)lsel));
    out[outIdx] = total_mean + alpha * top_mean - beta * bm;
  }
}

extern "C" void kernel_launch(void* const* d_in, const int* in_sizes, int n_in,
                              void* d_out, int out_size, void* d_ws, size_t ws_size,
                              hipStream_t stream) {
  (void)in_sizes; (void)n_in; (void)out_size;
  const float* q_emb = (const float*)d_in[0];
  const float* p_emb = (const float*)d_in[1];
  const void* q_mask = d_in[2];
  const void* p_mask = d_in[3];
  const float* alpha_raw = (const float*)d_in[4];
  const float* beta_raw = (const float*)d_in[5];
  float* out = (float*)d_out;

  if (ws_size >= NEED_T) {
    unsigned char* qt = (unsigned char*)d_ws;
    unsigned char* pt = qt + (size_t)NA_G * 16;
    hipLaunchKernelGGL(convert_pack, dim3((NA_G + NB_G) / 256), dim3(256), 0, stream,
                       q_emb, p_emb, qt, pt);
    hipLaunchKernelGGL((dpr_fused<1>), dim3(2048), dim3(TB), 0, stream,
                       q_emb, p_emb, q_mask, p_mask, alpha_raw, beta_raw, qt, pt, out);
  } else {
    hipLaunchKernelGGL((dpr_fused<0>), dim3(2048), dim3(TB), 0, stream,
                       q_emb, p_emb, q_mask, p_mask, alpha_raw, beta_raw,
                       (const unsigned char*)nullptr, (const unsigned char*)nullptr, out);
  }
}